// Round 13
// baseline (713.195 us; speedup 1.0000x reference)
//
#include <hip/hip_runtime.h>
#include <hip/hip_bf16.h>
#include <math.h>

#define NN 50000
#define EDGES 1600000
#define ETOT (EDGES + NN)
#define FINDIM 39
#define NPART 128
#define PSZ 391        // dsts per partition; 128*391 = 50048 >= NN
#define PCAP 14000     // capacity per partition (avg 12891, +9.8 sigma)
#define P1TILE 4096

__device__ __forceinline__ unsigned pack_bf16(float a, float b) {
    __hip_bfloat162 t;
    t.x = __float2bfloat16(a);
    t.y = __float2bfloat16(b);
    return *(unsigned*)&t;
}
__device__ __forceinline__ float2 unpack_bf16(unsigned w) {
    float2 r;
    r.x = __uint_as_float(w << 16);
    r.y = __uint_as_float(w & 0xffff0000u);
    return r;
}

__device__ __forceinline__ int src_at(const int* ei, int i, bool i32) {
    return i32 ? ei[i] : ei[2 * i];
}
__device__ __forceinline__ int dst_at(const int* ei, int i, bool i32) {
    return i32 ? ei[EDGES + i] : ei[2 * (EDGES + i)];
}

// ---------------- CSR pass 1 (self-detecting int32/int64): bucket into 128 partitions ----------------
__global__ __launch_bounds__(256) void pass1_kernel(const int* __restrict__ ei,
                                                    int* __restrict__ gcursor,
                                                    unsigned* __restrict__ pbuf) {
    __shared__ unsigned raw[P1TILE];
    __shared__ unsigned srt[P1TILE];
    __shared__ int pcnt[NPART], poff[NPART], pcur[NPART], gb[NPART];
    __shared__ int i32flag;
    int t = threadIdx.x;
    if (t == 0) i32flag = 0;
    __syncthreads();
    int chunk = (ETOT + gridDim.x - 1) / gridDim.x;
    int c0 = blockIdx.x * chunk;
    int c1 = c0 + chunk; if (c1 > ETOT) c1 = ETOT;
    int sb = c0 < EDGES - 64 ? c0 : 0;
    if (t < 64 && ei[2 * (sb + t) + 1] != 0) i32flag = 1;
    __syncthreads();
    bool i32 = (i32flag != 0);
    for (int t0 = c0; t0 < c1; t0 += P1TILE) {
        int tn = c1 - t0; if (tn > P1TILE) tn = P1TILE;
        if (t < NPART) { pcnt[t] = 0; pcur[t] = 0; }
        __syncthreads();
        for (int i = t; i < tn; i += 256) {
            int e = t0 + i;
            int s, d;
            if (e < EDGES) { s = src_at(ei, e, i32); d = dst_at(ei, e, i32); }
            else { s = d = e - EDGES; }
            raw[i] = ((unsigned)s << 16) | (unsigned)d;
            atomicAdd(&pcnt[d / PSZ], 1);
        }
        __syncthreads();
        if (t < NPART) poff[t] = pcnt[t];
        __syncthreads();
        for (int off = 1; off < NPART; off <<= 1) {
            int v = 0;
            if (t < NPART && t >= off) v = poff[t - off];
            __syncthreads();
            if (t < NPART) poff[t] += v;
            __syncthreads();
        }
        if (t < NPART) {
            poff[t] -= pcnt[t];                       // exclusive
            gb[t] = atomicAdd(&gcursor[t], pcnt[t]);  // global base for this tile's run
        }
        __syncthreads();
        for (int i = t; i < tn; i += 256) {
            unsigned r = raw[i];
            int part = (int)(r & 0xFFFFu) / PSZ;
            int pos = poff[part] + atomicAdd(&pcur[part], 1);
            srt[pos] = r;
        }
        __syncthreads();
        for (int i = t; i < tn; i += 256) {
            unsigned r = srt[i];
            int part = (int)(r & 0xFFFFu) / PSZ;
            int gpos = gb[part] + (i - poff[part]);
            if (gpos < PCAP) pbuf[(size_t)part * PCAP + gpos] = r;
        }
        __syncthreads();
    }
}

// ---------------- CSR pass 2: per-partition exact sort -> rowptr + colidx (pbase inline) ----------------
__global__ __launch_bounds__(256) void pass2_kernel(const unsigned* __restrict__ pbuf,
                                                    const int* __restrict__ gcursor,
                                                    int* __restrict__ rowptr,
                                                    int* __restrict__ colidx) {
    __shared__ unsigned recs[PCAP];                 // 56 KB
    __shared__ int lhist[PSZ], lexcl[PSZ], lcur[PSZ];
    __shared__ int psm[NPART];
    int p = blockIdx.x;
    int t = threadIdx.x;
    // inline prefix over the 128 partition totals
    if (t < NPART) psm[t] = gcursor[t];
    __syncthreads();
    for (int off = 1; off < NPART; off <<= 1) {
        int x = 0;
        if (t < NPART && t >= off) x = psm[t - off];
        __syncthreads();
        if (t < NPART) psm[t] += x;
        __syncthreads();
    }
    int n = gcursor[p]; if (n > PCAP) n = PCAP;
    int base = psm[p] - gcursor[p];
    if (p == NPART - 1 && t == 0) rowptr[NN] = psm[NPART - 1];   // == ETOT
    int d0 = p * PSZ;
    int nd = NN - d0; if (nd > PSZ) nd = PSZ;
    for (int i = t; i < nd; i += 256) { lhist[i] = 0; lcur[i] = 0; }
    __syncthreads();
    for (int i = t; i < n; i += 256) {
        unsigned r = pbuf[(size_t)p * PCAP + i];
        recs[i] = r;
        atomicAdd(&lhist[(int)(r & 0xFFFFu) - d0], 1);
    }
    __syncthreads();
    for (int i = t; i < nd; i += 256) lexcl[i] = lhist[i];
    __syncthreads();
    for (int off = 1; off < PSZ; off <<= 1) {
        int a0 = 0, a1 = 0;
        int i0 = t, i1 = t + 256;
        if (i0 < nd && i0 >= off) a0 = lexcl[i0 - off];
        if (i1 < nd && i1 >= off) a1 = lexcl[i1 - off];
        __syncthreads();
        if (i0 < nd) lexcl[i0] += a0;
        if (i1 < nd) lexcl[i1] += a1;
        __syncthreads();
    }
    for (int i = t; i < nd; i += 256) {
        lexcl[i] -= lhist[i];                        // exclusive
        rowptr[d0 + i] = base + lexcl[i];
    }
    __syncthreads();
    for (int i = t; i < n; i += 256) {
        unsigned r = recs[i];
        int li = (int)(r & 0xFFFFu) - d0;
        int pos = base + lexcl[li] + atomicAdd(&lcur[li], 1);
        colidx[pos] = (int)(r >> 16);
    }
}

// ---------------- generic GEMM (K=39 encoder-1 only) ----------------
template <int NC, bool RELU>
__global__ __launch_bounds__(256) void gemm_small_kernel(const float* __restrict__ A,
                                                         const float* __restrict__ B,
                                                         const float* __restrict__ bias,
                                                         float* __restrict__ C, int M, int K) {
    constexpr int TM = 32;
    constexpr int GROUPS = 256 / NC;
    constexpr int RPG = TM / GROUPS;
    constexpr int KC = 64;
    __shared__ float As[TM * 128];
    __shared__ float Bs[KC * NC];
    int t = threadIdx.x;
    int i0 = blockIdx.x * TM;

    int rows = M - i0; if (rows > TM) rows = TM;
    for (int idx = t; idx < rows * K; idx += 256) {
        int r = idx / K, k = idx - r * K;
        As[r * K + k] = A[(size_t)(i0 + r) * K + k];
    }

    int col = t % NC, grp = t / NC;
    int rg0 = grp * RPG;
    float acc[RPG];
#pragma unroll
    for (int r = 0; r < RPG; ++r) acc[r] = 0.f;

    for (int k0 = 0; k0 < K; k0 += KC) {
        int kc = K - k0; if (kc > KC) kc = KC;
        __syncthreads();
        for (int idx = t; idx < kc * NC; idx += 256) Bs[idx] = B[(size_t)k0 * NC + idx];
        __syncthreads();
        for (int k = 0; k < kc; ++k) {
            float bv = Bs[k * NC + col];
#pragma unroll
            for (int r = 0; r < RPG; ++r) acc[r] += As[(rg0 + r) * K + k0 + k] * bv;
        }
    }

    float bb = bias ? bias[col] : 0.f;
#pragma unroll
    for (int r = 0; r < RPG; ++r) {
        int i = i0 + rg0 + r;
        if (i < M) {
            float v = acc[r] + bb;
            if (RELU) v = v > 0.f ? v : 0.f;
            C[(size_t)i * NC + col] = v;
        }
    }
}

// ---------------- fast GEMM 128x128, 24KB LDS; EPI: packed-bf16 xp + es/ed ----------------
template <bool BIAS, bool EPI>
__global__ __launch_bounds__(256) void gemm128_kernel(const float* __restrict__ A,
                                                      const float* __restrict__ B,
                                                      const float* __restrict__ bias,
                                                      float* __restrict__ C,
                                                      unsigned* __restrict__ XP,
                                                      const float* __restrict__ a_s,
                                                      const float* __restrict__ a_d,
                                                      float* __restrict__ es,
                                                      float* __restrict__ ed, int M) {
    __shared__ float As[64 * 32];    // 8 KB : 64 rows x 32-k chunk
    __shared__ float Bs[32 * 128];   // 16 KB: 32-k chunk x 128 cols
    int t = threadIdx.x;
    int i0 = blockIdx.x * 64;
    int tc = t & 31;                 // cols tc*4 .. tc*4+3
    int tr = t >> 5;
    int r0 = tr * 8;
    int c0 = tc * 4;

    float acc[8][4];
#pragma unroll
    for (int i = 0; i < 8; ++i)
#pragma unroll
        for (int j = 0; j < 4; ++j) acc[i][j] = 0.f;

    for (int k0 = 0; k0 < 128; k0 += 32) {
        __syncthreads();
#pragma unroll
        for (int q = 0; q < 2; ++q) {
            int idx = t + q * 256;           // 0..511
            int r = idx >> 3, kq = idx & 7;
            float4 v4 = make_float4(0.f, 0.f, 0.f, 0.f);
            if (i0 + r < M) v4 = *(const float4*)&A[(size_t)(i0 + r) * 128 + k0 + kq * 4];
            *(float4*)&As[r * 32 + kq * 4] = v4;
        }
#pragma unroll
        for (int q = 0; q < 4; ++q) {
            int idx = (t + q * 256) * 4;
            *(float4*)&Bs[idx] = *(const float4*)&B[(size_t)k0 * 128 + idx];
        }
        __syncthreads();
#pragma unroll 8
        for (int k = 0; k < 32; k += 4) {
            float4 a4[8];
#pragma unroll
            for (int i = 0; i < 8; ++i)
                a4[i] = *(const float4*)&As[(r0 + i) * 32 + k];
            float4 b4[4];
#pragma unroll
            for (int kk = 0; kk < 4; ++kk)
                b4[kk] = *(const float4*)&Bs[(k + kk) * 128 + c0];
#pragma unroll
            for (int i = 0; i < 8; ++i) {
                const float* av = (const float*)&a4[i];
#pragma unroll
                for (int kk = 0; kk < 4; ++kk) {
                    acc[i][0] += av[kk] * b4[kk].x;
                    acc[i][1] += av[kk] * b4[kk].y;
                    acc[i][2] += av[kk] * b4[kk].z;
                    acc[i][3] += av[kk] * b4[kk].w;
                }
            }
        }
    }

    if (!EPI) {
        float4 bias4 = make_float4(0.f, 0.f, 0.f, 0.f);
        if (BIAS) bias4 = *(const float4*)&bias[c0];
#pragma unroll
        for (int i = 0; i < 8; ++i) {
            int row = i0 + r0 + i;
            if (row < M) {
                float4 o;
                o.x = acc[i][0] + bias4.x;
                o.y = acc[i][1] + bias4.y;
                o.z = acc[i][2] + bias4.z;
                o.w = acc[i][3] + bias4.w;
                *(float4*)&C[(size_t)row * 128 + c0] = o;
            }
        }
    } else {
#pragma unroll
        for (int i = 0; i < 8; ++i) {
            int row = i0 + r0 + i;
            if (row < M) {
                uint2 o;
                o.x = pack_bf16(acc[i][0], acc[i][1]);
                o.y = pack_bf16(acc[i][2], acc[i][3]);
                *(uint2*)&XP[(size_t)row * 64 + tc * 2] = o;
            }
        }
        int hd = tc >> 3;
        float4 s4 = *(const float4*)&a_s[c0];
        float4 d4 = *(const float4*)&a_d[c0];
#pragma unroll
        for (int i = 0; i < 8; ++i) {
            int row = i0 + r0 + i;
            float s = acc[i][0] * s4.x + acc[i][1] * s4.y + acc[i][2] * s4.z + acc[i][3] * s4.w;
            float d = acc[i][0] * d4.x + acc[i][1] * d4.y + acc[i][2] * d4.z + acc[i][3] * d4.w;
#pragma unroll
            for (int off = 4; off >= 1; off >>= 1) {
                s += __shfl_xor(s, off);
                d += __shfl_xor(d, off);
            }
            if ((tc & 7) == 0 && row < M) {
                es[row * 4 + hd] = s;
                ed[row * 4 + hd] = d;
            }
        }
    }
}

// ---------------- head GEMMs fully fused: h -> out (impact+timing), 24KB LDS ----------------
__global__ __launch_bounds__(256) void gemm_heads_kernel(const float* __restrict__ A,
                                                         const float* __restrict__ iw1,
                                                         const float* __restrict__ ib1,
                                                         const float* __restrict__ tw1,
                                                         const float* __restrict__ tb1,
                                                         const float* __restrict__ iw2,
                                                         const float* __restrict__ ib2,
                                                         const float* __restrict__ tw2,
                                                         const float* __restrict__ tb2,
                                                         float* __restrict__ out, int M) {
    __shared__ float As[64 * 32];
    __shared__ float Bs[32 * 128];
    int t = threadIdx.x;
    int i0 = blockIdx.x * 64;
    int tc = t & 31;
    int tr = t >> 5;
    int r0 = tr * 8;
    int c0 = tc * 4;                 // virtual col (0-63 impact, 64-127 timing)

    float acc[8][4];
#pragma unroll
    for (int i = 0; i < 8; ++i)
#pragma unroll
        for (int j = 0; j < 4; ++j) acc[i][j] = 0.f;

    for (int k0 = 0; k0 < 128; k0 += 32) {
        __syncthreads();
#pragma unroll
        for (int q = 0; q < 2; ++q) {
            int idx = t + q * 256;
            int r = idx >> 3, kq = idx & 7;
            float4 v4 = make_float4(0.f, 0.f, 0.f, 0.f);
            if (i0 + r < M) v4 = *(const float4*)&A[(size_t)(i0 + r) * 128 + k0 + kq * 4];
            *(float4*)&As[r * 32 + kq * 4] = v4;
        }
#pragma unroll
        for (int q = 0; q < 4; ++q) {
            int idx = (t + q * 256) * 4;       // flat into [32][128]
            int k = idx >> 7, cl = idx & 127;
            float4 v4 = (cl < 64)
                ? *(const float4*)&iw1[(size_t)(k0 + k) * 64 + cl]
                : *(const float4*)&tw1[(size_t)(k0 + k) * 64 + (cl - 64)];
            *(float4*)&Bs[idx] = v4;
        }
        __syncthreads();
#pragma unroll 8
        for (int k = 0; k < 32; k += 4) {
            float4 a4[8];
#pragma unroll
            for (int i = 0; i < 8; ++i)
                a4[i] = *(const float4*)&As[(r0 + i) * 32 + k];
            float4 b4[4];
#pragma unroll
            for (int kk = 0; kk < 4; ++kk)
                b4[kk] = *(const float4*)&Bs[(k + kk) * 128 + c0];
#pragma unroll
            for (int i = 0; i < 8; ++i) {
                const float* av = (const float*)&a4[i];
#pragma unroll
                for (int kk = 0; kk < 4; ++kk) {
                    acc[i][0] += av[kk] * b4[kk].x;
                    acc[i][1] += av[kk] * b4[kk].y;
                    acc[i][2] += av[kk] * b4[kk].z;
                    acc[i][3] += av[kk] * b4[kk].w;
                }
            }
        }
    }

    bool isimp = (tc < 16);
    int lc = isimp ? c0 : (c0 - 64);
    float v[8][4];
#pragma unroll
    for (int i = 0; i < 8; ++i)
#pragma unroll
        for (int j = 0; j < 4; ++j) {
            float b = isimp ? ib1[lc + j] : tb1[lc + j];
            float x = acc[i][j] + b;
            v[i][j] = x > 0.f ? x : 0.f;
        }
#pragma unroll
    for (int i = 0; i < 8; ++i) {
        int row = i0 + r0 + i;
        if (isimp) {
#pragma unroll
            for (int c = 0; c < 3; ++c) {
                float pc = v[i][0] * iw2[(lc + 0) * 3 + c] + v[i][1] * iw2[(lc + 1) * 3 + c]
                         + v[i][2] * iw2[(lc + 2) * 3 + c] + v[i][3] * iw2[(lc + 3) * 3 + c];
#pragma unroll
                for (int off = 8; off >= 1; off >>= 1) pc += __shfl_xor(pc, off);
                if (tc == 0 && row < M) out[(size_t)row * 3 + c] = pc + ib2[c];
            }
        } else {
#pragma unroll
            for (int d = 0; d < 2; ++d) {
                float pd = v[i][0] * tw2[(lc + 0) * 2 + d] + v[i][1] * tw2[(lc + 1) * 2 + d]
                         + v[i][2] * tw2[(lc + 2) * 2 + d] + v[i][3] * tw2[(lc + 3) * 2 + d];
#pragma unroll
                for (int off = 8; off >= 1; off >>= 1) pd += __shfl_xor(pd, off);
                if (tc == 16 && row < M) {
                    float a = pd + tb2[d];
                    float sp = a > 20.f ? a : log1pf(__expf(a));
                    out[(size_t)(NN * 3) + (size_t)row * 2 + d] = sp;
                }
            }
        }
    }
}

// ---------------- gat v7: bpermute-distributed weights, 32-bit saddr addressing ----------------
__global__ __launch_bounds__(256) void gat_kernel(const unsigned* __restrict__ xpk,
                                                  const float* __restrict__ es,
                                                  const float* __restrict__ ed,
                                                  const int* __restrict__ rowptr,
                                                  const int* __restrict__ colidx,
                                                  float* __restrict__ h,   // in-out (residual)
                                                  const float* __restrict__ bc,
                                                  const float* __restrict__ g,
                                                  const float* __restrict__ be) {
    int wv = threadIdx.x >> 6, l = threadIdx.x & 63;
    int v = blockIdx.x * 4 + wv;
    if (v >= NN) return;
    int s0 = rowptr[v], s1 = rowptr[v + 1];
    int hd = l >> 4;                       // head of channels 2l, 2l+1 (consumer role)
    int q4 = l & 3;                        // head this lane computes weights for (producer role)
    int e  = l >> 2;                       // edge slot this lane computes weights for
    float edq = ed[v * 4 + q4];
    float ax = 0.f, ay = 0.f, den = 0.f;

    for (int p = s0; p < s1; p += 16) {
        int n = s1 - p; if (n > 16) n = 16;
        // producer: lane j computes w for (edge j>>2, head j&3)
        int ureg = 0;
        float wreg = 0.f;
        if (e < n) {
            ureg = colidx[p + e];
            float tt = es[(unsigned)((ureg << 2) + q4)] + edq;
            tt = tt > 0.f ? tt : 0.2f * tt;
            wreg = __expf(tt);             // no max-shift: |e| small, softmax shift-invariant
        }
        int wbits = __float_as_int(wreg);
        // consumer: pull (u, w) from lane q*4+hd; one shared byte-index register
        int bidx = hd << 2;                // (q*4+hd)*4 = q*16 + hd*4
#pragma unroll 4
        for (int q = 0; q < n; ++q) {
            int u = __builtin_amdgcn_ds_bpermute(bidx, ureg);
            float w = __int_as_float(__builtin_amdgcn_ds_bpermute(bidx, wbits));
            bidx += 16;
            float2 x = unpack_bf16(xpk[(unsigned)((u << 6) + l)]);
            ax = fmaf(w, x.x, ax);
            ay = fmaf(w, x.y, ay);
            den += w;
        }
    }
    float rd = 1.f / den;

    float2 h2  = *(const float2*)&h[(size_t)v * 128 + 2 * l];
    float2 bc2 = *(const float2*)&bc[2 * l];
    float y0 = ax * rd + bc2.x + h2.x;
    float y1 = ay * rd + bc2.y + h2.y;

    float s = y0 + y1;
#pragma unroll
    for (int off = 32; off >= 1; off >>= 1) s += __shfl_xor(s, off);
    float mean = s * (1.f / 128.f);
    float d0 = y0 - mean, d1 = y1 - mean;
    float vv = d0 * d0 + d1 * d1;
#pragma unroll
    for (int off = 32; off >= 1; off >>= 1) vv += __shfl_xor(vv, off);
    float rstd = rsqrtf(vv * (1.f / 128.f) + 1e-5f);
    float2 g2  = *(const float2*)&g[2 * l];
    float2 be2 = *(const float2*)&be[2 * l];
    float z0 = d0 * rstd * g2.x + be2.x;
    float z1 = d1 * rstd * g2.y + be2.y;
    float2 o;
    o.x = z0 > 0.f ? z0 : 0.f;
    o.y = z1 > 0.f ? z1 : 0.f;
    *(float2*)&h[(size_t)v * 128 + 2 * l] = o;
}

extern "C" void kernel_launch(void* const* d_in, const int* in_sizes, int n_in,
                              void* d_out, int out_size, void* d_ws, size_t ws_size,
                              hipStream_t stream) {
    const float* x      = (const float*)d_in[0];
    const int*   ei     = (const int*)d_in[1];
    const float* enc_w1 = (const float*)d_in[2];
    const float* enc_b1 = (const float*)d_in[3];
    const float* enc_w2 = (const float*)d_in[4];
    const float* enc_b2 = (const float*)d_in[5];
    const float *W[3], *as_[3], *ad_[3], *bc[3], *g[3], *be[3];
    for (int l = 0; l < 3; ++l) {
        W[l]   = (const float*)d_in[6 + l * 6 + 0];
        as_[l] = (const float*)d_in[6 + l * 6 + 1];
        ad_[l] = (const float*)d_in[6 + l * 6 + 2];
        bc[l]  = (const float*)d_in[6 + l * 6 + 3];
        g[l]   = (const float*)d_in[6 + l * 6 + 4];
        be[l]  = (const float*)d_in[6 + l * 6 + 5];
    }
    const float* imp_w1 = (const float*)d_in[24];
    const float* imp_b1 = (const float*)d_in[25];
    const float* imp_w2 = (const float*)d_in[26];
    const float* imp_b2 = (const float*)d_in[27];
    const float* tim_w1 = (const float*)d_in[28];
    const float* tim_b1 = (const float*)d_in[29];
    const float* tim_w2 = (const float*)d_in[30];
    const float* tim_b2 = (const float*)d_in[31];

    int* gcursor = (int*)d_ws;               // NPART
    int* rowptr  = gcursor + NPART + 64;     // NN+1
    int* colidx  = rowptr + NN + 1;          // ETOT
    uintptr_t pb = (uintptr_t)(colidx + ETOT);
    pb = (pb + 255) & ~(uintptr_t)255;
    unsigned* pbuf = (unsigned*)pb;          // NPART*PCAP (7.2 MB)
    uintptr_t fb = (uintptr_t)(pbuf + (size_t)NPART * PCAP);
    fb = (fb + 255) & ~(uintptr_t)255;
    float* es = (float*)fb;                  // NN*4
    float* ed = es + (size_t)NN * 4;         // NN*4
    float* h  = ed + (size_t)NN * 4;         // NN*128 fp32
    float* xpf = h + (size_t)NN * 128;       // region sized NN*128 floats
    unsigned* xpk = (unsigned*)xpf;          // packed bf16 uses first half
    float* tmp = xpf;                        // enc1 scratch aliases (dead before xpk lives)

    hipMemsetAsync(gcursor, 0, NPART * sizeof(int), stream);
    pass1_kernel<<<512, 256, 0, stream>>>(ei, gcursor, pbuf);
    pass2_kernel<<<NPART, 256, 0, stream>>>(pbuf, gcursor, rowptr, colidx);

    const int GB64 = (NN + 63) / 64;
    gemm_small_kernel<128, true><<<(NN + 31) / 32, 256, 0, stream>>>(x, enc_w1, enc_b1, tmp, NN, FINDIM);
    gemm128_kernel<true, false><<<GB64, 256, 0, stream>>>(tmp, enc_w2, enc_b2, h, nullptr,
                                                          nullptr, nullptr, nullptr, nullptr, NN);

    for (int l = 0; l < 3; ++l) {
        gemm128_kernel<false, true><<<GB64, 256, 0, stream>>>(h, W[l], nullptr, nullptr, xpk,
                                                              as_[l], ad_[l], es, ed, NN);
        gat_kernel<<<(NN + 3) / 4, 256, 0, stream>>>(xpk, es, ed, rowptr, colidx, h,
                                                     bc[l], g[l], be[l]);
    }

    gemm_heads_kernel<<<GB64, 256, 0, stream>>>(h, imp_w1, imp_b1, tim_w1, tim_b1,
                                                imp_w2, imp_b2, tim_w2, tim_b2,
                                                (float*)d_out, NN);
}

// Round 14
// 570.363 us; speedup vs baseline: 1.2504x; 1.2504x over previous
//
#include <hip/hip_runtime.h>
#include <hip/hip_bf16.h>
#include <math.h>

#define NN 50000
#define EDGES 1600000
#define ETOT (EDGES + NN)
#define FINDIM 39
#define NPART 256
#define PSZ 196        // dsts per partition; 256*196 = 50176 >= NN
#define PCAP 7100      // capacity per partition (avg 6468, +7.9 sigma)
#define P1TILE 4096

__device__ __forceinline__ unsigned pack_bf16(float a, float b) {
    __hip_bfloat162 t;
    t.x = __float2bfloat16(a);
    t.y = __float2bfloat16(b);
    return *(unsigned*)&t;
}
__device__ __forceinline__ float2 unpack_bf16(unsigned w) {
    float2 r;
    r.x = __uint_as_float(w << 16);
    r.y = __uint_as_float(w & 0xffff0000u);
    return r;
}

__device__ __forceinline__ int src_at(const int* ei, int i, bool i32) {
    return i32 ? ei[i] : ei[2 * i];
}
__device__ __forceinline__ int dst_at(const int* ei, int i, bool i32) {
    return i32 ? ei[EDGES + i] : ei[2 * (EDGES + i)];
}

// ---------------- CSR pass 1 (self-detecting int32/int64): bucket into 256 partitions ----------------
__global__ __launch_bounds__(256) void pass1_kernel(const int* __restrict__ ei,
                                                    int* __restrict__ gcursor,
                                                    unsigned* __restrict__ pbuf) {
    __shared__ unsigned raw[P1TILE];
    __shared__ unsigned srt[P1TILE];
    __shared__ int pcnt[NPART], poff[NPART], pcur[NPART], gb[NPART];
    __shared__ int i32flag;
    int t = threadIdx.x;
    if (t == 0) i32flag = 0;
    __syncthreads();
    int chunk = (ETOT + gridDim.x - 1) / gridDim.x;
    int c0 = blockIdx.x * chunk;
    int c1 = c0 + chunk; if (c1 > ETOT) c1 = ETOT;
    int sb = c0 < EDGES - 64 ? c0 : 0;
    if (t < 64 && ei[2 * (sb + t) + 1] != 0) i32flag = 1;
    __syncthreads();
    bool i32 = (i32flag != 0);
    for (int t0 = c0; t0 < c1; t0 += P1TILE) {
        int tn = c1 - t0; if (tn > P1TILE) tn = P1TILE;
        pcnt[t] = 0; pcur[t] = 0;
        __syncthreads();
        for (int i = t; i < tn; i += 256) {
            int e = t0 + i;
            int s, d;
            if (e < EDGES) { s = src_at(ei, e, i32); d = dst_at(ei, e, i32); }
            else { s = d = e - EDGES; }
            raw[i] = ((unsigned)s << 16) | (unsigned)d;
            atomicAdd(&pcnt[d / PSZ], 1);
        }
        __syncthreads();
        poff[t] = pcnt[t];
        __syncthreads();
        for (int off = 1; off < NPART; off <<= 1) {
            int v = (t >= off) ? poff[t - off] : 0;
            __syncthreads();
            poff[t] += v;
            __syncthreads();
        }
        poff[t] -= pcnt[t];                       // exclusive
        gb[t] = atomicAdd(&gcursor[t], pcnt[t]);  // global base for this tile's run
        __syncthreads();
        for (int i = t; i < tn; i += 256) {
            unsigned r = raw[i];
            int part = (int)(r & 0xFFFFu) / PSZ;
            int pos = poff[part] + atomicAdd(&pcur[part], 1);
            srt[pos] = r;
        }
        __syncthreads();
        for (int i = t; i < tn; i += 256) {
            unsigned r = srt[i];
            int part = (int)(r & 0xFFFFu) / PSZ;
            int gpos = gb[part] + (i - poff[part]);
            if (gpos < PCAP) pbuf[(size_t)part * PCAP + gpos] = r;
        }
        __syncthreads();
    }
}

// ---------------- CSR pass 2: per-partition exact sort -> rowptr + colidx (pbase inline) ----------------
__global__ __launch_bounds__(256) void pass2_kernel(const unsigned* __restrict__ pbuf,
                                                    const int* __restrict__ gcursor,
                                                    int* __restrict__ rowptr,
                                                    int* __restrict__ colidx) {
    __shared__ unsigned recs[PCAP];                 // 28.4 KB
    __shared__ int lhist[PSZ], lexcl[PSZ], lcur[PSZ];
    __shared__ int psm[NPART];
    int p = blockIdx.x;
    int t = threadIdx.x;
    // inline prefix over the 256 partition totals
    psm[t] = gcursor[t];
    __syncthreads();
    for (int off = 1; off < NPART; off <<= 1) {
        int x = (t >= off) ? psm[t - off] : 0;
        __syncthreads();
        psm[t] += x;
        __syncthreads();
    }
    int n = gcursor[p]; if (n > PCAP) n = PCAP;
    int base = psm[p] - gcursor[p];
    if (p == NPART - 1 && t == 0) rowptr[NN] = psm[NPART - 1];   // == ETOT
    int d0 = p * PSZ;
    int nd = NN - d0; if (nd > PSZ) nd = PSZ;
    if (nd < 0) nd = 0;
    for (int i = t; i < nd; i += 256) { lhist[i] = 0; lcur[i] = 0; }
    __syncthreads();
    for (int i = t; i < n; i += 256) {
        unsigned r = pbuf[(size_t)p * PCAP + i];
        recs[i] = r;
        atomicAdd(&lhist[(int)(r & 0xFFFFu) - d0], 1);
    }
    __syncthreads();
    for (int i = t; i < nd; i += 256) lexcl[i] = lhist[i];
    __syncthreads();
    for (int off = 1; off < PSZ; off <<= 1) {
        int a0 = 0;
        if (t < nd && t >= off) a0 = lexcl[t - off];
        __syncthreads();
        if (t < nd) lexcl[t] += a0;
        __syncthreads();
    }
    for (int i = t; i < nd; i += 256) {
        lexcl[i] -= lhist[i];                        // exclusive
        rowptr[d0 + i] = base + lexcl[i];
    }
    __syncthreads();
    for (int i = t; i < n; i += 256) {
        unsigned r = recs[i];
        int li = (int)(r & 0xFFFFu) - d0;
        int pos = base + lexcl[li] + atomicAdd(&lcur[li], 1);
        colidx[pos] = (int)(r >> 16);
    }
}

// ---------------- generic GEMM (K=39 encoder-1 only) ----------------
template <int NC, bool RELU>
__global__ __launch_bounds__(256) void gemm_small_kernel(const float* __restrict__ A,
                                                         const float* __restrict__ B,
                                                         const float* __restrict__ bias,
                                                         float* __restrict__ C, int M, int K) {
    constexpr int TM = 32;
    constexpr int GROUPS = 256 / NC;
    constexpr int RPG = TM / GROUPS;
    constexpr int KC = 64;
    __shared__ float As[TM * 128];
    __shared__ float Bs[KC * NC];
    int t = threadIdx.x;
    int i0 = blockIdx.x * TM;

    int rows = M - i0; if (rows > TM) rows = TM;
    for (int idx = t; idx < rows * K; idx += 256) {
        int r = idx / K, k = idx - r * K;
        As[r * K + k] = A[(size_t)(i0 + r) * K + k];
    }

    int col = t % NC, grp = t / NC;
    int rg0 = grp * RPG;
    float acc[RPG];
#pragma unroll
    for (int r = 0; r < RPG; ++r) acc[r] = 0.f;

    for (int k0 = 0; k0 < K; k0 += KC) {
        int kc = K - k0; if (kc > KC) kc = KC;
        __syncthreads();
        for (int idx = t; idx < kc * NC; idx += 256) Bs[idx] = B[(size_t)k0 * NC + idx];
        __syncthreads();
        for (int k = 0; k < kc; ++k) {
            float bv = Bs[k * NC + col];
#pragma unroll
            for (int r = 0; r < RPG; ++r) acc[r] += As[(rg0 + r) * K + k0 + k] * bv;
        }
    }

    float bb = bias ? bias[col] : 0.f;
#pragma unroll
    for (int r = 0; r < RPG; ++r) {
        int i = i0 + rg0 + r;
        if (i < M) {
            float v = acc[r] + bb;
            if (RELU) v = v > 0.f ? v : 0.f;
            C[(size_t)i * NC + col] = v;
        }
    }
}

// ---------------- fast GEMM 128x128, 24KB LDS; EPI: packed-bf16 xp + es/ed ----------------
template <bool BIAS, bool EPI>
__global__ __launch_bounds__(256) void gemm128_kernel(const float* __restrict__ A,
                                                      const float* __restrict__ B,
                                                      const float* __restrict__ bias,
                                                      float* __restrict__ C,
                                                      unsigned* __restrict__ XP,
                                                      const float* __restrict__ a_s,
                                                      const float* __restrict__ a_d,
                                                      float* __restrict__ es,
                                                      float* __restrict__ ed, int M) {
    __shared__ float As[64 * 32];    // 8 KB : 64 rows x 32-k chunk
    __shared__ float Bs[32 * 128];   // 16 KB: 32-k chunk x 128 cols
    int t = threadIdx.x;
    int i0 = blockIdx.x * 64;
    int tc = t & 31;                 // cols tc*4 .. tc*4+3
    int tr = t >> 5;
    int r0 = tr * 8;
    int c0 = tc * 4;

    float acc[8][4];
#pragma unroll
    for (int i = 0; i < 8; ++i)
#pragma unroll
        for (int j = 0; j < 4; ++j) acc[i][j] = 0.f;

    for (int k0 = 0; k0 < 128; k0 += 32) {
        __syncthreads();
#pragma unroll
        for (int q = 0; q < 2; ++q) {
            int idx = t + q * 256;           // 0..511
            int r = idx >> 3, kq = idx & 7;
            float4 v4 = make_float4(0.f, 0.f, 0.f, 0.f);
            if (i0 + r < M) v4 = *(const float4*)&A[(size_t)(i0 + r) * 128 + k0 + kq * 4];
            *(float4*)&As[r * 32 + kq * 4] = v4;
        }
#pragma unroll
        for (int q = 0; q < 4; ++q) {
            int idx = (t + q * 256) * 4;
            *(float4*)&Bs[idx] = *(const float4*)&B[(size_t)k0 * 128 + idx];
        }
        __syncthreads();
#pragma unroll 8
        for (int k = 0; k < 32; k += 4) {
            float4 a4[8];
#pragma unroll
            for (int i = 0; i < 8; ++i)
                a4[i] = *(const float4*)&As[(r0 + i) * 32 + k];
            float4 b4[4];
#pragma unroll
            for (int kk = 0; kk < 4; ++kk)
                b4[kk] = *(const float4*)&Bs[(k + kk) * 128 + c0];
#pragma unroll
            for (int i = 0; i < 8; ++i) {
                const float* av = (const float*)&a4[i];
#pragma unroll
                for (int kk = 0; kk < 4; ++kk) {
                    acc[i][0] += av[kk] * b4[kk].x;
                    acc[i][1] += av[kk] * b4[kk].y;
                    acc[i][2] += av[kk] * b4[kk].z;
                    acc[i][3] += av[kk] * b4[kk].w;
                }
            }
        }
    }

    if (!EPI) {
        float4 bias4 = make_float4(0.f, 0.f, 0.f, 0.f);
        if (BIAS) bias4 = *(const float4*)&bias[c0];
#pragma unroll
        for (int i = 0; i < 8; ++i) {
            int row = i0 + r0 + i;
            if (row < M) {
                float4 o;
                o.x = acc[i][0] + bias4.x;
                o.y = acc[i][1] + bias4.y;
                o.z = acc[i][2] + bias4.z;
                o.w = acc[i][3] + bias4.w;
                *(float4*)&C[(size_t)row * 128 + c0] = o;
            }
        }
    } else {
#pragma unroll
        for (int i = 0; i < 8; ++i) {
            int row = i0 + r0 + i;
            if (row < M) {
                uint2 o;
                o.x = pack_bf16(acc[i][0], acc[i][1]);
                o.y = pack_bf16(acc[i][2], acc[i][3]);
                *(uint2*)&XP[(size_t)row * 64 + tc * 2] = o;
            }
        }
        int hd = tc >> 3;
        float4 s4 = *(const float4*)&a_s[c0];
        float4 d4 = *(const float4*)&a_d[c0];
#pragma unroll
        for (int i = 0; i < 8; ++i) {
            int row = i0 + r0 + i;
            float s = acc[i][0] * s4.x + acc[i][1] * s4.y + acc[i][2] * s4.z + acc[i][3] * s4.w;
            float d = acc[i][0] * d4.x + acc[i][1] * d4.y + acc[i][2] * d4.z + acc[i][3] * d4.w;
#pragma unroll
            for (int off = 4; off >= 1; off >>= 1) {
                s += __shfl_xor(s, off);
                d += __shfl_xor(d, off);
            }
            if ((tc & 7) == 0 && row < M) {
                es[row * 4 + hd] = s;
                ed[row * 4 + hd] = d;
            }
        }
    }
}

// ---------------- head GEMMs fully fused: h -> out (impact+timing), 24KB LDS ----------------
__global__ __launch_bounds__(256) void gemm_heads_kernel(const float* __restrict__ A,
                                                         const float* __restrict__ iw1,
                                                         const float* __restrict__ ib1,
                                                         const float* __restrict__ tw1,
                                                         const float* __restrict__ tb1,
                                                         const float* __restrict__ iw2,
                                                         const float* __restrict__ ib2,
                                                         const float* __restrict__ tw2,
                                                         const float* __restrict__ tb2,
                                                         float* __restrict__ out, int M) {
    __shared__ float As[64 * 32];
    __shared__ float Bs[32 * 128];
    int t = threadIdx.x;
    int i0 = blockIdx.x * 64;
    int tc = t & 31;
    int tr = t >> 5;
    int r0 = tr * 8;
    int c0 = tc * 4;                 // virtual col (0-63 impact, 64-127 timing)

    float acc[8][4];
#pragma unroll
    for (int i = 0; i < 8; ++i)
#pragma unroll
        for (int j = 0; j < 4; ++j) acc[i][j] = 0.f;

    for (int k0 = 0; k0 < 128; k0 += 32) {
        __syncthreads();
#pragma unroll
        for (int q = 0; q < 2; ++q) {
            int idx = t + q * 256;
            int r = idx >> 3, kq = idx & 7;
            float4 v4 = make_float4(0.f, 0.f, 0.f, 0.f);
            if (i0 + r < M) v4 = *(const float4*)&A[(size_t)(i0 + r) * 128 + k0 + kq * 4];
            *(float4*)&As[r * 32 + kq * 4] = v4;
        }
#pragma unroll
        for (int q = 0; q < 4; ++q) {
            int idx = (t + q * 256) * 4;       // flat into [32][128]
            int k = idx >> 7, cl = idx & 127;
            float4 v4 = (cl < 64)
                ? *(const float4*)&iw1[(size_t)(k0 + k) * 64 + cl]
                : *(const float4*)&tw1[(size_t)(k0 + k) * 64 + (cl - 64)];
            *(float4*)&Bs[idx] = v4;
        }
        __syncthreads();
#pragma unroll 8
        for (int k = 0; k < 32; k += 4) {
            float4 a4[8];
#pragma unroll
            for (int i = 0; i < 8; ++i)
                a4[i] = *(const float4*)&As[(r0 + i) * 32 + k];
            float4 b4[4];
#pragma unroll
            for (int kk = 0; kk < 4; ++kk)
                b4[kk] = *(const float4*)&Bs[(k + kk) * 128 + c0];
#pragma unroll
            for (int i = 0; i < 8; ++i) {
                const float* av = (const float*)&a4[i];
#pragma unroll
                for (int kk = 0; kk < 4; ++kk) {
                    acc[i][0] += av[kk] * b4[kk].x;
                    acc[i][1] += av[kk] * b4[kk].y;
                    acc[i][2] += av[kk] * b4[kk].z;
                    acc[i][3] += av[kk] * b4[kk].w;
                }
            }
        }
    }

    bool isimp = (tc < 16);
    int lc = isimp ? c0 : (c0 - 64);
    float v[8][4];
#pragma unroll
    for (int i = 0; i < 8; ++i)
#pragma unroll
        for (int j = 0; j < 4; ++j) {
            float b = isimp ? ib1[lc + j] : tb1[lc + j];
            float x = acc[i][j] + b;
            v[i][j] = x > 0.f ? x : 0.f;
        }
#pragma unroll
    for (int i = 0; i < 8; ++i) {
        int row = i0 + r0 + i;
        if (isimp) {
#pragma unroll
            for (int c = 0; c < 3; ++c) {
                float pc = v[i][0] * iw2[(lc + 0) * 3 + c] + v[i][1] * iw2[(lc + 1) * 3 + c]
                         + v[i][2] * iw2[(lc + 2) * 3 + c] + v[i][3] * iw2[(lc + 3) * 3 + c];
#pragma unroll
                for (int off = 8; off >= 1; off >>= 1) pc += __shfl_xor(pc, off);
                if (tc == 0 && row < M) out[(size_t)row * 3 + c] = pc + ib2[c];
            }
        } else {
#pragma unroll
            for (int d = 0; d < 2; ++d) {
                float pd = v[i][0] * tw2[(lc + 0) * 2 + d] + v[i][1] * tw2[(lc + 1) * 2 + d]
                         + v[i][2] * tw2[(lc + 2) * 2 + d] + v[i][3] * tw2[(lc + 3) * 2 + d];
#pragma unroll
                for (int off = 8; off >= 1; off >>= 1) pd += __shfl_xor(pd, off);
                if (tc == 16 && row < M) {
                    float a = pd + tb2[d];
                    float sp = a > 20.f ? a : log1pf(__expf(a));
                    out[(size_t)(NN * 3) + (size_t)row * 2 + d] = sp;
                }
            }
        }
    }
}

// ---------------- gat v6r: fused weights, 32-bit addressing, branch-free leaky ----------------
__global__ __launch_bounds__(256) void gat_kernel(const unsigned* __restrict__ xpk,
                                                  const float* __restrict__ es,
                                                  const float* __restrict__ ed,
                                                  const int* __restrict__ rowptr,
                                                  const int* __restrict__ colidx,
                                                  float* __restrict__ h,   // in-out (residual)
                                                  const float* __restrict__ bc,
                                                  const float* __restrict__ g,
                                                  const float* __restrict__ be) {
    int wv = threadIdx.x >> 6, l = threadIdx.x & 63;
    int v = blockIdx.x * 4 + wv;
    if (v >= NN) return;
    int s0 = rowptr[v], s1 = rowptr[v + 1];
    int hd = l >> 4;                       // head of channels 2l, 2l+1
    float edv = ed[(unsigned)(v << 2) + hd];
    float ax = 0.f, ay = 0.f, den = 0.f;   // den identical across the 16 lanes of a head
    int p = s0;
    for (; p + 8 <= s1; p += 8) {          // 8 gathers in flight
        int u[8];
#pragma unroll
        for (int q = 0; q < 8; ++q) u[q] = colidx[p + q];
        unsigned xw[8];
#pragma unroll
        for (int q = 0; q < 8; ++q) xw[q] = xpk[(unsigned)(u[q] << 6) + l];
        float w[8];
#pragma unroll
        for (int q = 0; q < 8; ++q) {
            float e = es[(unsigned)(u[q] << 2) + hd] + edv;
            e = fmaxf(e, 0.2f * e);        // leaky_relu, slope<1 => max form
            w[q] = __expf(e);              // no max-shift: |e| small, softmax shift-invariant
        }
#pragma unroll
        for (int q = 0; q < 8; ++q) {
            float2 x = unpack_bf16(xw[q]);
            ax = fmaf(w[q], x.x, ax);
            ay = fmaf(w[q], x.y, ay);
            den += w[q];
        }
    }
    for (; p < s1; ++p) {
        int u = colidx[p];
        float e = es[(unsigned)(u << 2) + hd] + edv;
        e = fmaxf(e, 0.2f * e);
        float w = __expf(e);
        float2 x = unpack_bf16(xpk[(unsigned)(u << 6) + l]);
        ax = fmaf(w, x.x, ax);
        ay = fmaf(w, x.y, ay);
        den += w;
    }
    float rd = 1.f / den;

    float2 h2  = *(const float2*)&h[(size_t)v * 128 + 2 * l];
    float2 bc2 = *(const float2*)&bc[2 * l];
    float y0 = ax * rd + bc2.x + h2.x;
    float y1 = ay * rd + bc2.y + h2.y;

    float s = y0 + y1;
#pragma unroll
    for (int off = 32; off >= 1; off >>= 1) s += __shfl_xor(s, off);
    float mean = s * (1.f / 128.f);
    float d0 = y0 - mean, d1 = y1 - mean;
    float vv = d0 * d0 + d1 * d1;
#pragma unroll
    for (int off = 32; off >= 1; off >>= 1) vv += __shfl_xor(vv, off);
    float rstd = rsqrtf(vv * (1.f / 128.f) + 1e-5f);
    float2 g2  = *(const float2*)&g[2 * l];
    float2 be2 = *(const float2*)&be[2 * l];
    float z0 = d0 * rstd * g2.x + be2.x;
    float z1 = d1 * rstd * g2.y + be2.y;
    float2 o;
    o.x = z0 > 0.f ? z0 : 0.f;
    o.y = z1 > 0.f ? z1 : 0.f;
    *(float2*)&h[(size_t)v * 128 + 2 * l] = o;
}

extern "C" void kernel_launch(void* const* d_in, const int* in_sizes, int n_in,
                              void* d_out, int out_size, void* d_ws, size_t ws_size,
                              hipStream_t stream) {
    const float* x      = (const float*)d_in[0];
    const int*   ei     = (const int*)d_in[1];
    const float* enc_w1 = (const float*)d_in[2];
    const float* enc_b1 = (const float*)d_in[3];
    const float* enc_w2 = (const float*)d_in[4];
    const float* enc_b2 = (const float*)d_in[5];
    const float *W[3], *as_[3], *ad_[3], *bc[3], *g[3], *be[3];
    for (int l = 0; l < 3; ++l) {
        W[l]   = (const float*)d_in[6 + l * 6 + 0];
        as_[l] = (const float*)d_in[6 + l * 6 + 1];
        ad_[l] = (const float*)d_in[6 + l * 6 + 2];
        bc[l]  = (const float*)d_in[6 + l * 6 + 3];
        g[l]   = (const float*)d_in[6 + l * 6 + 4];
        be[l]  = (const float*)d_in[6 + l * 6 + 5];
    }
    const float* imp_w1 = (const float*)d_in[24];
    const float* imp_b1 = (const float*)d_in[25];
    const float* imp_w2 = (const float*)d_in[26];
    const float* imp_b2 = (const float*)d_in[27];
    const float* tim_w1 = (const float*)d_in[28];
    const float* tim_b1 = (const float*)d_in[29];
    const float* tim_w2 = (const float*)d_in[30];
    const float* tim_b2 = (const float*)d_in[31];

    int* gcursor = (int*)d_ws;               // NPART
    int* rowptr  = gcursor + NPART + 64;     // NN+1
    int* colidx  = rowptr + NN + 1;          // ETOT
    uintptr_t pb = (uintptr_t)(colidx + ETOT);
    pb = (pb + 255) & ~(uintptr_t)255;
    unsigned* pbuf = (unsigned*)pb;          // NPART*PCAP (7.3 MB)
    uintptr_t fb = (uintptr_t)(pbuf + (size_t)NPART * PCAP);
    fb = (fb + 255) & ~(uintptr_t)255;
    float* es = (float*)fb;                  // NN*4
    float* ed = es + (size_t)NN * 4;         // NN*4
    float* h  = ed + (size_t)NN * 4;         // NN*128 fp32
    float* xpf = h + (size_t)NN * 128;       // region sized NN*128 floats
    unsigned* xpk = (unsigned*)xpf;          // packed bf16 uses first half
    float* tmp = xpf;                        // enc1 scratch aliases (dead before xpk lives)

    hipMemsetAsync(gcursor, 0, NPART * sizeof(int), stream);
    pass1_kernel<<<512, 256, 0, stream>>>(ei, gcursor, pbuf);
    pass2_kernel<<<NPART, 256, 0, stream>>>(pbuf, gcursor, rowptr, colidx);

    const int GB64 = (NN + 63) / 64;
    gemm_small_kernel<128, true><<<(NN + 31) / 32, 256, 0, stream>>>(x, enc_w1, enc_b1, tmp, NN, FINDIM);
    gemm128_kernel<true, false><<<GB64, 256, 0, stream>>>(tmp, enc_w2, enc_b2, h, nullptr,
                                                          nullptr, nullptr, nullptr, nullptr, NN);

    for (int l = 0; l < 3; ++l) {
        gemm128_kernel<false, true><<<GB64, 256, 0, stream>>>(h, W[l], nullptr, nullptr, xpk,
                                                              as_[l], ad_[l], es, ed, NN);
        gat_kernel<<<(NN + 3) / 4, 256, 0, stream>>>(xpk, es, ed, rowptr, colidx, h,
                                                     bc[l], g[l], be[l]);
    }

    gemm_heads_kernel<<<GB64, 256, 0, stream>>>(h, imp_w1, imp_b1, tim_w1, tim_b1,
                                                imp_w2, imp_b2, tim_w2, tim_b2,
                                                (float*)d_out, NN);
}